// Round 3
// baseline (281.010 us; speedup 1.0000x reference)
//
#include <hip/hip_runtime.h>
#include <hip/hip_bf16.h>

#define BATCH 4
#define N_PER 300
#define IN_DIM 256
#define KEY_DIM 32
#define FH 160
#define FW 160
#define HW (FH * FW)                 // 25600
#define NQ (BATCH * N_PER)           // 1200
#define Q_ELEMS (NQ * KEY_DIM)       // 38400 fp32 in ws: qry_feats [n][c]
#define KWT_ELEMS (IN_DIM * KEY_DIM) // 8192 fp32 in ws: key_w transposed [c][o]
#define PREP_TOTAL (Q_ELEMS + KWT_ELEMS)   // 46592 = 182 * 256 exactly

// ---------------------------------------------------------------------------
// Prep: ws[0..38400) = qry_feats[n][c] = in_feats @ qry_w.T + qry_b
//       ws[38400..46592) = kwT[c][o] = key_w[o][c]  (transposed so the main
//       kernel reads contiguous wave-uniform 32-float rows -> scalar loads)
// ---------------------------------------------------------------------------
__global__ __launch_bounds__(256) void prep_kernel(
        const float* __restrict__ in_feats,
        const float* __restrict__ qry_w,
        const float* __restrict__ qry_b,
        const float* __restrict__ key_w,
        float* __restrict__ ws) {
    int gid = blockIdx.x * 256 + threadIdx.x;
    if (gid < Q_ELEMS) {
        int n = gid >> 5;      // query index 0..1199
        int c = gid & 31;      // key-dim channel 0..31
        const float* __restrict__ fr = in_feats + n * IN_DIM;
        const float* __restrict__ wr = qry_w + c * IN_DIM;
        float a0 = qry_b[c], a1 = 0.f, a2 = 0.f, a3 = 0.f;
        #pragma unroll 4
        for (int k = 0; k < IN_DIM; k += 4) {
            a0 += fr[k + 0] * wr[k + 0];
            a1 += fr[k + 1] * wr[k + 1];
            a2 += fr[k + 2] * wr[k + 2];
            a3 += fr[k + 3] * wr[k + 3];
        }
        ws[gid] = (a0 + a1) + (a2 + a3);   // ws[n*32 + c]
    } else {
        int i = gid - Q_ELEMS;             // 0..8191
        int c = i >> 5;                    // 0..255
        int o = i & 31;                    // 0..31
        ws[gid] = key_w[o * IN_DIM + c];   // kwT[c*32 + o]
    }
}

// ---------------------------------------------------------------------------
// Fused main: per pixel p of batch b:
//   phase 1: key[o] = key_b[o] + sum_c kwT[c][o] * feat_map[b,c,p]   (K=256)
//   phase 2: for n in 0..299: out[b,n,p] = dot32(q[b,n,:], key)      (K=32)
// key_map never touches HBM. q / kwT / key_b reads are wave-uniform fp32
// (scalarizable); feat_map reads & out stores are lane-coalesced fp32.
// ---------------------------------------------------------------------------
__global__ __launch_bounds__(256) void main_kernel(
        const float* __restrict__ feat_map,
        const float* __restrict__ key_b,
        const float* __restrict__ ws,
        float* __restrict__ out) {
    const int b = blockIdx.y;
    const int p = blockIdx.x * 256 + threadIdx.x;   // 0..25599 (exact fit)

    const float* __restrict__ fb  = feat_map + ((size_t)b * IN_DIM) * HW + p;
    const float* __restrict__ kwT = ws + Q_ELEMS;

    float key[KEY_DIM];
    #pragma unroll
    for (int o = 0; o < KEY_DIM; ++o) key[o] = key_b[o];

    // Phase 1: stream feat_map over c (coalesced), 32 indep FMA chains.
    #pragma unroll 8
    for (int c = 0; c < IN_DIM; ++c) {
        float f = fb[(size_t)c * HW];
        const float* __restrict__ kr = kwT + c * KEY_DIM;
        #pragma unroll
        for (int o = 0; o < KEY_DIM; ++o)
            key[o] += kr[o] * f;
    }

    // Phase 2: 300 dot-32s against wave-uniform q rows.
    const float* __restrict__ qb = ws + (size_t)b * N_PER * KEY_DIM;
    float* __restrict__ ob = out + ((size_t)b * N_PER) * HW + p;
    for (int n = 0; n < N_PER; ++n) {
        const float* __restrict__ qn = qb + n * KEY_DIM;
        float a0 = 0.f, a1 = 0.f, a2 = 0.f, a3 = 0.f;
        #pragma unroll
        for (int c = 0; c < KEY_DIM; c += 4) {
            a0 += qn[c + 0] * key[c + 0];
            a1 += qn[c + 1] * key[c + 1];
            a2 += qn[c + 2] * key[c + 2];
            a3 += qn[c + 3] * key[c + 3];
        }
        ob[(size_t)n * HW] = (a0 + a1) + (a2 + a3);
    }
}

extern "C" void kernel_launch(void* const* d_in, const int* in_sizes, int n_in,
                              void* d_out, int out_size, void* d_ws, size_t ws_size,
                              hipStream_t stream) {
    const float* in_feats = (const float*)d_in[0];  // [1200, 256]
    const float* feat_map = (const float*)d_in[1];  // [4, 256, 160, 160]
    const float* qry_w    = (const float*)d_in[2];  // [32, 256]
    const float* qry_b    = (const float*)d_in[3];  // [32]
    const float* key_w    = (const float*)d_in[4];  // [32, 256]
    const float* key_b    = (const float*)d_in[5];  // [32]
    float* ws  = (float*)d_ws;                      // needs 46592*4 B
    float* out = (float*)d_out;                     // [1200, 160, 160] fp32

    // Prep: 38400 + 8192 = 46592 outputs = 182 blocks * 256 exactly.
    prep_kernel<<<dim3(PREP_TOTAL / 256), dim3(256), 0, stream>>>(
        in_feats, qry_w, qry_b, key_w, ws);

    // Main: 100 pixel-tiles (256 px each) x 4 batches.
    dim3 grid(HW / 256, BATCH);
    main_kernel<<<grid, dim3(256), 0, stream>>>(feat_map, key_b, ws, out);
}